// Round 10
// baseline (49.551 us; speedup 1.0000x reference)
//
#include <hip/hip_runtime.h>

typedef unsigned short ushort_t;
typedef unsigned int uint_t;
typedef short short8 __attribute__((ext_vector_type(8)));
typedef float f32x4 __attribute__((ext_vector_type(4)));

namespace {

template<int CTRL, int RM>
__device__ __forceinline__ float dpp_mov0(float v) {
  return __int_as_float(__builtin_amdgcn_update_dpp(
      0, __float_as_int(v), CTRL, RM, 0xF, false));
}
template<int CTRL, int RM>
__device__ __forceinline__ float dpp_mov1(float v) {
  return __int_as_float(__builtin_amdgcn_update_dpp(
      0x3f800000, __float_as_int(v), CTRL, RM, 0xF, false));
}

__device__ __forceinline__ float rl(float v, int k) {
  return __int_as_float(__builtin_amdgcn_readlane(__float_as_int(v), k));
}

// A_bar apply via joint 2-var linear-recurrence DPP scan (HW-verified r1-r9).
struct Hoist {
  float cs0, cs1, cs2, cs3, cs4, cs5;
  float gs0, gs1, gs2, gs3, gs4, gs5;
  float r, inv_d, hr, alpha, k2;
};

__device__ __forceinline__ Hoist make_hoist(float dt, int n) {
  float h = 0.5f * dt, fn = (float)n;
  float r = sqrtf(2.f * fn + 1.f);
  float d = 1.f + h * (fn + 1.f);
  float inv_d = 1.f / d;
  float g = (1.f - h * fn) * inv_d;
  float c = g - 1.f;
  Hoist H;
  H.r = r; H.inv_d = inv_d; H.hr = h * r;
  H.alpha = 1.f + h * fn;
  H.k2 = r * (2.f - d) * inv_d;
#define COEF_STEP(IDX, CTRL, RM)                                        \
  H.cs##IDX = c; H.gs##IDX = g;                                         \
  { float cP = dpp_mov0<CTRL, RM>(c);                                   \
    float gP = dpp_mov1<CTRL, RM>(g);                                   \
    c = fmaf(g, cP, c); g = g * gP; }
  COEF_STEP(0, 0x111, 0xF)
  COEF_STEP(1, 0x112, 0xF)
  COEF_STEP(2, 0x114, 0xF)
  COEF_STEP(3, 0x118, 0xF)
  COEF_STEP(4, 0x142, 0xA)
  COEF_STEP(5, 0x143, 0xC)
#undef COEF_STEP
  return H;
}

__device__ __forceinline__ float abar_apply(float x, const Hoist& H) {
  float w1 = H.r * x, w2 = H.k2 * x;
#define APPLY_STEP(IDX, CTRL, RM)                                       \
  { float w1P = dpp_mov0<CTRL, RM>(w1);                                 \
    float w2P = dpp_mov0<CTRL, RM>(w2);                                 \
    w2 = fmaf(H.cs##IDX, w1P, fmaf(H.gs##IDX, w2P, w2));                \
    w1 += w1P; }
  APPLY_STEP(0, 0x111, 0xF)
  APPLY_STEP(1, 0x112, 0xF)
  APPLY_STEP(2, 0x114, 0xF)
  APPLY_STEP(3, 0x118, 0xF)
  APPLY_STEP(4, 0x142, 0xA)
  APPLY_STEP(5, 0x143, 0xC)
#undef APPLY_STEP
  float tp = dpp_mov0<0x138, 0xF>(w2);           // wave_shr:1
  return H.inv_d * fmaf(-H.hr, w1 + tp, H.alpha * x);
}

template<int CTRL, int RM>
__device__ __forceinline__ void linrec_step(float& G, float& W) {
  float Wo = dpp_mov0<CTRL, RM>(W);
  float Go = dpp_mov1<CTRL, RM>(G);
  W = fmaf(G, Wo, W);
  G *= Go;
}
__device__ __forceinline__ float lhs_solve(float z, const Hoist& H) {
  float G = H.gs0, W = H.r * z * H.inv_d;
  linrec_step<0x111, 0xF>(G, W);
  linrec_step<0x112, 0xF>(G, W);
  linrec_step<0x114, 0xF>(G, W);
  linrec_step<0x118, 0xF>(G, W);
  linrec_step<0x142, 0xA>(G, W);
  linrec_step<0x143, 0xC>(G, W);
  float sp = dpp_mov0<0x138, 0xF>(W);
  return (z - H.hr * sp) * H.inv_d;
}

__device__ __forceinline__ float softplus_dt(float ldt) {
  return log1pf(expf(ldt)) + 1e-6f;
}

__device__ __forceinline__ void load_row_g(const float* __restrict__ base,
                                           float (&pc)[64]) {
  const float4* p4 = (const float4*)base;
  #pragma unroll
  for (int q = 0; q < 16; ++q) {
    float4 f = p4[q];
    pc[4*q+0] = f.x; pc[4*q+1] = f.y; pc[4*q+2] = f.z; pc[4*q+3] = f.w;
  }
}

__device__ __forceinline__ float qapply(const float (&pc)[64], float u) {
  float a0 = 0.f, a1 = 0.f, a2 = 0.f, a3 = 0.f;
  #pragma unroll
  for (int k = 0; k < 64; k += 4) {
    a0 = fmaf(pc[k + 0], rl(u, k + 0), a0);
    a1 = fmaf(pc[k + 1], rl(u, k + 1), a1);
    a2 = fmaf(pc[k + 2], rl(u, k + 2), a2);
    a3 = fmaf(pc[k + 3], rl(u, k + 3), a3);
  }
  return (a0 + a1) + (a2 + a3);
}

// error-compensated bf16 split (R7-verified numerics)
__device__ __forceinline__ void bsplit(float v, ushort_t& h, ushort_t& l) {
  uint_t uv = __float_as_uint(v);
  float hf = __uint_as_float(uv & 0xFFFF0000u);
  uint_t lv = __float_as_uint(v - hf);
  h = (ushort_t)(uv >> 16);
  l = (ushort_t)(lv >> 16);
}

} // namespace

// K1: blocks 0-63: power chains (snapshot A^j cols j=1..63 scattered row-major;
// A^64 -> PRM row-major). Blocks 64+: per-d B_bar scan + bf16 splits of
// B_bar and C into A-side arrays and the j=0 / i=0 output slots.
__global__ __launch_bounds__(64) void hippo_prep(
    const float* __restrict__ B, const float* __restrict__ C,
    const float* __restrict__ ldt_p, float* __restrict__ AjRM,
    float* __restrict__ PRM, ushort_t* __restrict__ Bh, ushort_t* __restrict__ Bl,
    ushort_t* __restrict__ Ch, ushort_t* __restrict__ Cl,
    ushort_t* __restrict__ Vh, ushort_t* __restrict__ Vl,
    ushort_t* __restrict__ Uh, ushort_t* __restrict__ Ul) {
  const int lane = threadIdx.x;
  const int bid = blockIdx.x;
  const float dt = softplus_dt(ldt_p[0]);
  const Hoist H = make_hoist(dt, lane);
  if (bid < 64) {
    const int m = bid;
    float x = (lane == m) ? 1.f : 0.f;
    #pragma unroll 1
    for (int s = 1; s <= 64; ++s) {
      x = abar_apply(x, H);
      if (s < 64) AjRM[s * 4096 + lane * 64 + m] = x;   // A^s[n][k] row-major
      else        PRM[lane * 64 + m] = x;               // P = A^64 row-major
    }
  } else {
    const int d = bid - 64;
    float bb = lhs_solve(dt * B[d * 64 + lane], H);
    ushort_t h, l;
    bsplit(bb, h, l);
    Bh[d * 64 + lane] = h;               Bl[d * 64 + lane] = l;
    Vh[(size_t)d * 4096 + lane] = h;     Vl[(size_t)d * 4096 + lane] = l;  // j=0
    float cc = C[d * 64 + lane];
    bsplit(cc, h, l);
    Ch[d * 64 + lane] = h;               Cl[d * 64 + lane] = l;
    Uh[(size_t)d * 2048 + lane] = h;     Ul[(size_t)d * 2048 + lane] = l;  // i=0
  }
}

// K1b: P^i columns by 30 serial matvecs; store (P^i)^T row-major (coalesced):
// PiT[i][m][n] = P^i[n][m], i = 1..31.
__global__ __launch_bounds__(64) void hippo_ppow(const float* __restrict__ PRM,
                                                 float* __restrict__ PiT) {
  const int lane = threadIdx.x;
  const int m = blockIdx.x;
  float pc[64];
  load_row_g(PRM + lane * 64, pc);       // pc[k] = P[lane][k]
  float x = PRM[lane * 64 + m];          // col m of P
  PiT[4096 + m * 64 + lane] = x;
  #pragma unroll 1
  for (int i = 2; i <= 31; ++i) {
    x = qapply(pc, x);                   // col m of P^i
    PiT[i * 4096 + m * 64 + lane] = x;
  }
}

// K2: 94 batched GEMMs (1024 x 64 x 64), MFMA bf16-split.
//  s<63:  V_j[d,n] = sum_k Bbar[d,k] * A^j[n,k]   (j = s+1)
//  s>=63: U_i[d,n] = sum_k C[d,k]    * P^i[k,n]   (i = s-62; B = PiT rows)
// B-matrix staged f32 in XOR-swizzled LDS; A-side bf16 frags from global.
__global__ __launch_bounds__(256) void hippo_gemm(
    const ushort_t* __restrict__ Bh, const ushort_t* __restrict__ Bl,
    const ushort_t* __restrict__ Ch, const ushort_t* __restrict__ Cl,
    const float* __restrict__ AjRM, const float* __restrict__ PiT,
    ushort_t* __restrict__ Vh, ushort_t* __restrict__ Vl,
    ushort_t* __restrict__ Uh, ushort_t* __restrict__ Ul, int MT) {
  __shared__ __align__(16) float Bs[64 * 64];
  const int s = blockIdx.x / MT;
  const int mt = blockIdx.x % MT;
  const int tau = threadIdx.x;
  const int lane = tau & 63;
  const int w = tau >> 6;
  const bool isV = (s < 63);
  const int j = isV ? (s + 1) : (s - 62);
  const float* Msrc = isV ? (AjRM + j * 4096) : (PiT + j * 4096);
  const ushort_t* Ah = isV ? Bh : Ch;
  const ushort_t* Al = isV ? Bl : Cl;

  // stage B-matrix, 16B-chunk XOR swizzle within each 64-float row
  #pragma unroll
  for (int p = 0; p < 4; ++p) {
    const int idx = tau + 256 * p;                 // float4 index
    const int row = idx >> 4, c4 = idx & 15;
    f32x4 f = *(const f32x4*)(Msrc + idx * 4);
    *(f32x4*)&Bs[row * 64 + ((c4 ^ (row & 15)) << 2)] = f;
  }
  __syncthreads();

  const int arow = lane & 15, kg = lane >> 4;
  const int drow = mt * 64 + w * 16 + arow;
  f32x4 acc0 = {0.f,0.f,0.f,0.f}, acc1 = {0.f,0.f,0.f,0.f};
  f32x4 acc2 = {0.f,0.f,0.f,0.f}, acc3 = {0.f,0.f,0.f,0.f};
  #pragma unroll
  for (int k0 = 0; k0 < 2; ++k0) {
    const size_t aoff = (size_t)drow * 64 + k0 * 32 + kg * 8;
    short8 ah = *(const short8*)(Ah + aoff);
    short8 al = *(const short8*)(Al + aoff);
    #pragma unroll
    for (int nt = 0; nt < 4; ++nt) {
      const int nrow = nt * 16 + arow;
      const int c4a = k0 * 8 + kg * 2;
      f32x4 f0 = *(const f32x4*)&Bs[nrow * 64 + ((c4a ^ (nrow & 15)) << 2)];
      f32x4 f1 = *(const f32x4*)&Bs[nrow * 64 + (((c4a + 1) ^ (nrow & 15)) << 2)];
      short8 bh, bl;
      #pragma unroll
      for (int e = 0; e < 4; ++e) {
        ushort_t hh, ll;
        bsplit(f0[e], hh, ll); bh[e] = (short)hh; bl[e] = (short)ll;
        bsplit(f1[e], hh, ll); bh[4 + e] = (short)hh; bl[4 + e] = (short)ll;
      }
      f32x4 a = (nt == 0) ? acc0 : (nt == 1) ? acc1 : (nt == 2) ? acc2 : acc3;
      a = __builtin_amdgcn_mfma_f32_16x16x32_bf16(ah, bh, a, 0, 0, 0);
      a = __builtin_amdgcn_mfma_f32_16x16x32_bf16(al, bh, a, 0, 0, 0);
      a = __builtin_amdgcn_mfma_f32_16x16x32_bf16(ah, bl, a, 0, 0, 0);
      if (nt == 0) acc0 = a; else if (nt == 1) acc1 = a;
      else if (nt == 2) acc2 = a; else acc3 = a;
    }
  }
  ushort_t* Oh = isV ? Vh : Uh;
  ushort_t* Ol = isV ? Vl : Ul;
  const int jd = isV ? 64 : 32;
  #pragma unroll
  for (int nt = 0; nt < 4; ++nt) {
    f32x4 a = (nt == 0) ? acc0 : (nt == 1) ? acc1 : (nt == 2) ? acc2 : acc3;
    #pragma unroll
    for (int r = 0; r < 4; ++r) {
      const int dd = mt * 64 + w * 16 + kg * 4 + r;    // C/D row (m89-verified)
      const int nn = nt * 16 + arow;                   // C/D col
      const size_t off = ((size_t)dd * jd + j) * 64 + nn;
      ushort_t hh, ll;
      bsplit(a[r], hh, ll);
      Oh[off] = hh;
      Ol[off] = ll;
    }
  }
}

// K3: per d, K[d, i*64+j] = U_i . V_j — R7-verified MFMA epilogue, frags
// loaded directly from frag-ready global arrays (zero LDS, zero chains).
__global__ __launch_bounds__(256) void hippo_out(
    const float* __restrict__ Dv,
    const ushort_t* __restrict__ Uh, const ushort_t* __restrict__ Ul,
    const ushort_t* __restrict__ Vh, const ushort_t* __restrict__ Vl,
    float* __restrict__ out) {
  const int d = blockIdx.x;
  const int tau = threadIdx.x;
  const int lane = tau & 63;
  const int w = tau >> 6;
  const int it = w & 1, jp = w >> 1;
  const int arow = lane & 15, kg = lane >> 4;
  f32x4 acc0 = {0.f,0.f,0.f,0.f}, acc1 = {0.f,0.f,0.f,0.f};
  const int ia = (it << 4) + arow;
  const int jv0 = (jp << 5) + arow;
  const int jv1 = jv0 + 16;
  const size_t ub = (size_t)d * 2048;
  const size_t vb = (size_t)d * 4096;
  #pragma unroll
  for (int k0 = 0; k0 < 2; ++k0) {
    const int ko = k0 * 32 + kg * 8;
    short8 ah  = *(const short8*)(Uh + ub + ia * 64 + ko);
    short8 al  = *(const short8*)(Ul + ub + ia * 64 + ko);
    short8 b0h = *(const short8*)(Vh + vb + jv0 * 64 + ko);
    short8 b0l = *(const short8*)(Vl + vb + jv0 * 64 + ko);
    short8 b1h = *(const short8*)(Vh + vb + jv1 * 64 + ko);
    short8 b1l = *(const short8*)(Vl + vb + jv1 * 64 + ko);
    acc0 = __builtin_amdgcn_mfma_f32_16x16x32_bf16(ah, b0h, acc0, 0, 0, 0);
    acc0 = __builtin_amdgcn_mfma_f32_16x16x32_bf16(al, b0h, acc0, 0, 0, 0);
    acc0 = __builtin_amdgcn_mfma_f32_16x16x32_bf16(ah, b0l, acc0, 0, 0, 0);
    acc1 = __builtin_amdgcn_mfma_f32_16x16x32_bf16(ah, b1h, acc1, 0, 0, 0);
    acc1 = __builtin_amdgcn_mfma_f32_16x16x32_bf16(al, b1h, acc1, 0, 0, 0);
    acc1 = __builtin_amdgcn_mfma_f32_16x16x32_bf16(ah, b1l, acc1, 0, 0, 0);
  }
  #pragma unroll
  for (int r = 0; r < 4; ++r) {
    const int i = (it << 4) + (kg << 2) + r;
    const int j0 = (jp << 5) + arow;
    float y0 = acc0[r];
    if (i == 0 && j0 == 0) y0 += Dv[d];
    out[((size_t)d << 11) + (i << 6) + j0] = y0;
    out[((size_t)d << 11) + (i << 6) + j0 + 16] = acc1[r];
  }
}

extern "C" void kernel_launch(void* const* d_in, const int* in_sizes, int n_in,
                              void* d_out, int out_size, void* d_ws, size_t ws_size,
                              hipStream_t stream) {
  const float* B   = (const float*)d_in[0];
  const float* C   = (const float*)d_in[1];
  const float* Dv  = (const float*)d_in[2];
  const float* ldt = (const float*)d_in[3];
  const int d_model = in_sizes[2];        // 1024
  const int MT = d_model / 64;            // 16

  char* ws = (char*)d_ws;
  size_t o = 0;
  float* AjRM = (float*)(ws + o); o += (size_t)64 * 4096 * 4;     // 1 MiB
  float* PRM  = (float*)(ws + o); o += 4096 * 4;                  // 16 KiB
  float* PiT  = (float*)(ws + o); o += (size_t)32 * 4096 * 4;     // 512 KiB
  ushort_t* Bh = (ushort_t*)(ws + o); o += (size_t)d_model * 64 * 2;
  ushort_t* Bl = (ushort_t*)(ws + o); o += (size_t)d_model * 64 * 2;
  ushort_t* Ch = (ushort_t*)(ws + o); o += (size_t)d_model * 64 * 2;
  ushort_t* Cl = (ushort_t*)(ws + o); o += (size_t)d_model * 64 * 2;
  ushort_t* Vh = (ushort_t*)(ws + o); o += (size_t)d_model * 4096 * 2;  // 8 MiB
  ushort_t* Vl = (ushort_t*)(ws + o); o += (size_t)d_model * 4096 * 2;
  ushort_t* Uh = (ushort_t*)(ws + o); o += (size_t)d_model * 2048 * 2;  // 4 MiB
  ushort_t* Ul = (ushort_t*)(ws + o); o += (size_t)d_model * 2048 * 2;

  hippo_prep<<<64 + d_model, 64, 0, stream>>>(B, C, ldt, AjRM, PRM,
                                              Bh, Bl, Ch, Cl, Vh, Vl, Uh, Ul);
  hippo_ppow<<<64, 64, 0, stream>>>(PRM, PiT);
  hippo_gemm<<<94 * MT, 256, 0, stream>>>(Bh, Bl, Ch, Cl, AjRM, PiT,
                                          Vh, Vl, Uh, Ul, MT);
  hippo_out<<<d_model, 256, 0, stream>>>(Dv, Uh, Ul, Vh, Vl, (float*)d_out);
}